// Round 3
// baseline (720.866 us; speedup 1.0000x reference)
//
#include <hip/hip_runtime.h>

typedef unsigned short ushort_t;
typedef __bf16 bf16x8 __attribute__((ext_vector_type(8)));
typedef float f32x4 __attribute__((ext_vector_type(4)));

#define T_ 10
#define N_ 30000
#define F_ 256
#define H_ 128
#define L_ 5
#define YR_ 5
#define NSTEP 5
#define MROWS_ENC (T_*N_)      /* 300000 */
#define MROWS_GRU (YR_*N_)     /* 150000 */
#define GRU_ROWS 32            /* rows per block -> 2 blocks/CU */

/* ---- workspace layout (bytes) ---- */
#define OFF_EMB   ((size_t)0)
#define SZ_EMB    ((size_t)T_*N_*H_*2)          /* 76,800,000 */
#define OFF_WENC  (OFF_EMB + SZ_EMB)
#define SZ_WENC   ((size_t)F_*H_*2)             /* 65,536 */
#define OFF_WIH   (OFF_WENC + SZ_WENC)
#define SZ_W3H    ((size_t)H_*3*H_*2)           /* 98,304 */
#define OFF_WHH   (OFF_WIH + SZ_W3H)
#define OFF_ACC   (OFF_WHH + SZ_W3H)            /* 2 floats: [0]=l_time_sum, [1]=l_pred_sum */

/* ---- helpers ---- */
__device__ __forceinline__ unsigned int bfbits(float x){
    unsigned int u = __float_as_uint(x);
    return (u + 0x7fffu + ((u >> 16) & 1u)) >> 16;   /* RNE f32->bf16 */
}
__device__ __forceinline__ unsigned int pack2(float lo, float hi){
    return bfbits(lo) | (bfbits(hi) << 16);
}
__device__ __forceinline__ float b2f(ushort_t u){
    return __uint_as_float(((unsigned int)u) << 16);
}
__device__ __forceinline__ f32x4 mfma16(bf16x8 a, bf16x8 b, f32x4 c){
    return __builtin_amdgcn_mfma_f32_16x16x32_bf16(a, b, c, 0, 0, 0);
}
__device__ __forceinline__ float fexp2_(float x){ return __builtin_amdgcn_exp2f(x); }
__device__ __forceinline__ float frcp_(float x){ return __builtin_amdgcn_rcpf(x); }
__device__ __forceinline__ float sigm_(float x){ return frcp_(1.f + fexp2_(-1.44269504f*x)); }
__device__ __forceinline__ float tanhfast_(float x){ return 1.f - 2.f*frcp_(1.f + fexp2_(2.88539008f*x)); }
__device__ __forceinline__ float softplus_(float x){
    float ax = fabsf(x);
    return fmaxf(x, 0.f) + log1pf(fexp2_(-1.44269504f*ax));
}
__device__ __forceinline__ float wave_sum(float v){
#pragma unroll
    for (int o = 32; o > 0; o >>= 1) v += __shfl_down(v, o, 64);
    return v;
}
/* LDS-only barrier: waits ds ops but leaves global prefetch loads (vmcnt) in
   flight across the barrier (unlike __syncthreads(), which drains vmcnt(0)). */
__device__ __forceinline__ void bar_lds(){
    asm volatile("s_waitcnt lgkmcnt(0)" ::: "memory");
    __builtin_amdgcn_s_barrier();
    __builtin_amdgcn_sched_barrier(0);
}

/* ---- prep: transpose+convert weights to bf16, zero accumulators ---- */
__global__ void prep_kernel(const float* __restrict__ We, const float* __restrict__ Wih,
                            const float* __restrict__ Whh,
                            ushort_t* __restrict__ Wet, ushort_t* __restrict__ Wiht,
                            ushort_t* __restrict__ Whht, float* __restrict__ accv)
{
    int i = blockIdx.x * 256 + threadIdx.x;
    if (i < 2) accv[i] = 0.f;
    if (i < F_*H_){                       /* Wet[h][f] = We[f][h] */
        int h = i >> 8, f = i & 255;
        Wet[i] = (ushort_t)bfbits(We[f*H_ + h]);
    }
    if (i < 3*H_*H_){                     /* W*t[c][k] = W[k][c] */
        int c = i >> 7, k = i & 127;
        Wiht[i] = (ushort_t)bfbits(Wih[k*(3*H_) + c]);
        Whht[i] = (ushort_t)bfbits(Whh[k*(3*H_) + c]);
    }
}

/* ---- encoder: emb = relu(X @ W_enc), bf16 out [T*N][128] ---- */
__global__ __launch_bounds__(256, 2) void enc_kernel(const float* __restrict__ X,
                                                     const ushort_t* __restrict__ Wet,
                                                     ushort_t* __restrict__ emb)
{
    __shared__ __attribute__((aligned(16))) ushort_t Xl[128*40];  /* [row][k] pitch 40 */
    __shared__ __attribute__((aligned(16))) ushort_t Wl[128*40];  /* [col][k] pitch 40 */
    const int tid = threadIdx.x;
    const int wv = tid >> 6, lane = tid & 63;
    const int m = lane & 15, q = lane >> 4;
    const int rowbase = blockIdx.x * 128;

    f32x4 acc[8][2];
#pragma unroll
    for (int a = 0; a < 8; ++a)
#pragma unroll
        for (int b = 0; b < 2; ++b)
            acc[a][b] = (f32x4){0.f, 0.f, 0.f, 0.f};

    const int srow = tid >> 1, shalf = tid & 1;
    int xrow = rowbase + srow; if (xrow > MROWS_ENC - 1) xrow = MROWS_ENC - 1;
    const float*    xp   = X   + (size_t)xrow * F_ + shalf * 16;
    const ushort_t* wp   = Wet + srow * F_ + shalf * 16;
    ushort_t*       xdst = &Xl[srow * 40 + shalf * 16];
    ushort_t*       wdst = &Wl[srow * 40 + shalf * 16];

    /* prologue: load ks=0 chunk into registers */
    float4 v0 = *(const float4*)(xp);
    float4 v1 = *(const float4*)(xp + 4);
    float4 v2 = *(const float4*)(xp + 8);
    float4 v3 = *(const float4*)(xp + 12);
    uint4  w0 = *(const uint4*)(wp);
    uint4  w1 = *(const uint4*)(wp + 8);

    for (int ks = 0; ks < 8; ++ks){
        /* pack current chunk -> LDS */
        uint4 p0, p1;
        p0.x = pack2(v0.x, v0.y); p0.y = pack2(v0.z, v0.w);
        p0.z = pack2(v1.x, v1.y); p0.w = pack2(v1.z, v1.w);
        p1.x = pack2(v2.x, v2.y); p1.y = pack2(v2.z, v2.w);
        p1.z = pack2(v3.x, v3.y); p1.w = pack2(v3.z, v3.w);
        *(uint4*)xdst       = p0;
        *(uint4*)(xdst + 8) = p1;
        *(uint4*)wdst       = w0;
        *(uint4*)(wdst + 8) = w1;

        /* prefetch next chunk (issued before the MFMA phase; consumed next iter) */
        if (ks < 7){
            const float*    xs   = xp + (ks + 1) * 32;
            const ushort_t* wsrc = wp + (ks + 1) * 32;
            v0 = *(const float4*)(xs);
            v1 = *(const float4*)(xs + 4);
            v2 = *(const float4*)(xs + 8);
            v3 = *(const float4*)(xs + 12);
            w0 = *(const uint4*)(wsrc);
            w1 = *(const uint4*)(wsrc + 8);
        }

        bar_lds();   /* writes visible; prefetch stays in flight */

        bf16x8 af[8];
#pragma unroll
        for (int rt = 0; rt < 8; ++rt)
            af[rt] = *reinterpret_cast<const bf16x8*>(&Xl[(rt*16 + m)*40 + q*8]);
        bf16x8 b0 = *reinterpret_cast<const bf16x8*>(&Wl[(wv*32 +      m)*40 + q*8]);
        bf16x8 b1 = *reinterpret_cast<const bf16x8*>(&Wl[(wv*32 + 16 + m)*40 + q*8]);
#pragma unroll
        for (int rt = 0; rt < 8; ++rt){
            acc[rt][0] = mfma16(af[rt], b0, acc[rt][0]);
            acc[rt][1] = mfma16(af[rt], b1, acc[rt][1]);
        }

        bar_lds();   /* reads done before next iteration's staging writes */
    }

#pragma unroll
    for (int rt = 0; rt < 8; ++rt)
#pragma unroll
        for (int ct = 0; ct < 2; ++ct){
            const int col = wv*32 + ct*16 + m;
#pragma unroll
            for (int i = 0; i < 4; ++i){
                int row = rowbase + rt*16 + q*4 + i;
                if (row < MROWS_ENC){
                    float v = acc[rt][ct][i];
                    v = v > 0.f ? v : 0.f;
                    emb[(size_t)row * H_ + col] = (ushort_t)bfbits(v);
                }
            }
        }
}

/* ---- l_time: mean_n,t sum_h (emb[t]-emb[t+1])^2 ---- */
__global__ __launch_bounds__(256) void ltime_kernel(const ushort_t* __restrict__ emb,
                                                    float* __restrict__ accv)
{
    const int g = blockIdx.x * 256 + threadIdx.x;   /* 480000 = 30000*16 chunks of 8 */
    const int base = g * 8;
    float s = 0.f;
    uint4 pv = *(const uint4*)(emb + base);
#pragma unroll
    for (int t = 1; t < T_; ++t){
        uint4 cv = *(const uint4*)(emb + (size_t)t * N_ * H_ + base);
        const unsigned int pa[4] = {pv.x, pv.y, pv.z, pv.w};
        const unsigned int ca[4] = {cv.x, cv.y, cv.z, cv.w};
#pragma unroll
        for (int j = 0; j < 4; ++j){
            float al = __uint_as_float(pa[j] << 16), ah = __uint_as_float(pa[j] & 0xffff0000u);
            float bl = __uint_as_float(ca[j] << 16), bh = __uint_as_float(ca[j] & 0xffff0000u);
            float d0 = al - bl, d1 = ah - bh;
            s += d0*d0 + d1*d1;
        }
        pv = cv;
    }
    s = wave_sum(s);
    __shared__ float red[4];
    const int lane = threadIdx.x & 63, wv = threadIdx.x >> 6;
    if (lane == 0) red[wv] = s;
    __syncthreads();
    if (threadIdx.x == 0) atomicAdd(&accv[0], red[0] + red[1] + red[2] + red[3]);
}

/* ---- GRU + heads + prediction loss ----
   Al is chunk-XOR-swizzled: logical 16B-chunk c of row r lives at chunk
   c ^ ((r&3)<<2). Kills the 8-way bank conflict of the pitch-272B
   ds_read_b128 fragment reads (bank-start was 4*(m+q) mod 32). Write and
   read use the same swizzle (both-sides-or-neither). Heads loss is computed
   with 8 lanes/row (one horizon per lane) so each wave issues one erfc
   chain instead of five. */
__global__ __launch_bounds__(512, 4) void gru_kernel(const ushort_t* __restrict__ emb,
                                                     const ushort_t* __restrict__ Wiht,
                                                     const ushort_t* __restrict__ Whht,
                                                     const float* __restrict__ bih,
                                                     const float* __restrict__ bhh,
                                                     const float* __restrict__ Wheads,
                                                     const float* __restrict__ bheads,
                                                     const float* __restrict__ Yv,
                                                     const int* __restrict__ years,
                                                     float* __restrict__ accv)
{
    __shared__ __attribute__((aligned(16))) ushort_t Al[2][GRU_ROWS*136];  /* pitch 136 */
    __shared__ float Whl[3*H_];
    __shared__ float red[8];
    __shared__ float eLds[GRU_ROWS], mLds[GRU_ROWS], iLds[GRU_ROWS];
    const int tid = threadIdx.x;
    const int wv = tid >> 6, lane = tid & 63;
    const int m = lane & 15, q = lane >> 4;
    const int rowbase = blockIdx.x * GRU_ROWS;

    /* swizzle constants: read offset (shorts) for logical chunk ks*4+q of a
       row with (row&3)==m&3 is ((ks<<5) ^ xr5) + q8 */
    const int xr5 = (m & 3) << 5;
    const int q8  = q * 8;

    if (tid < 3*H_) Whl[tid] = Wheads[tid];

    /* per-lane gate biases (column = g*128 + wv*16 + m); bh0/bh1 folded into gx */
    const int cb = wv*16 + m;
    const int c16 = cb >> 3, cb7 = cb & 7;       /* h-write chunk + intra-chunk */
    const float bi0 = bih[cb] + bhh[cb];
    const float bi1 = bih[128 + cb] + bhh[128 + cb];
    const float bi2 = bih[256 + cb];
    const float bh2 = bhh[256 + cb];

    /* W_ih fragments in registers: wave owns cols [16*wv,16*wv+16) of each gate */
    bf16x8 wf[3][4];
#pragma unroll
    for (int g = 0; g < 3; ++g)
#pragma unroll
        for (int ks = 0; ks < 4; ++ks)
            wf[g][ks] = *reinterpret_cast<const bf16x8*>(
                Wiht + (size_t)(g*128 + cb)*H_ + ks*32 + q*8);

    /* stage v tile (gathered rows of emb) into Al[0], swizzled chunks */
    {
        int r = tid >> 4, ch = tid & 15;
        int gr = rowbase + r; if (gr > MROWS_GRU - 1) gr = MROWS_GRU - 1;
        int yy = gr / N_;
        int n  = gr - yy * N_;
        int yr = years[yy];
        uint4 d = *(const uint4*)(emb + ((size_t)(yr*N_ + n))*H_ + ch*8);
        *(uint4*)&Al[0][r*136 + (ch ^ ((r & 3) << 2))*8] = d;
    }
    __syncthreads();

    /* gx = v @ W_ih + b_ih (+ b_hh for r,z gates) */
    f32x4 gx[2][3];
#pragma unroll
    for (int rt = 0; rt < 2; ++rt)
#pragma unroll
        for (int g = 0; g < 3; ++g)
            gx[rt][g] = (f32x4){0.f, 0.f, 0.f, 0.f};
#pragma unroll
    for (int ks = 0; ks < 4; ++ks){
        bf16x8 a[2];
#pragma unroll
        for (int rt = 0; rt < 2; ++rt)
            a[rt] = *reinterpret_cast<const bf16x8*>(
                &Al[0][(rt*16 + m)*136 + (((ks << 5) ^ xr5) + q8)]);
#pragma unroll
        for (int rt = 0; rt < 2; ++rt)
#pragma unroll
            for (int g = 0; g < 3; ++g)
                gx[rt][g] = mfma16(a[rt], wf[g][ks], gx[rt][g]);
    }
#pragma unroll
    for (int rt = 0; rt < 2; ++rt)
#pragma unroll
        for (int i = 0; i < 4; ++i){
            gx[rt][0][i] += bi0; gx[rt][1][i] += bi1; gx[rt][2][i] += bi2;
        }

    /* swap register weights to W_hh */
#pragma unroll
    for (int g = 0; g < 3; ++g)
#pragma unroll
        for (int ks = 0; ks < 4; ++ks)
            wf[g][ks] = *reinterpret_cast<const bf16x8*>(
                Whht + (size_t)(g*128 + cb)*H_ + ks*32 + q*8);

    f32x4 h[2];
#pragma unroll
    for (int rt = 0; rt < 2; ++rt) h[rt] = (f32x4){0.f, 0.f, 0.f, 0.f};

    /* step 0: h = 0 -> gh = 0 -> h = (1-z)*n */
#pragma unroll
    for (int rt = 0; rt < 2; ++rt)
#pragma unroll
        for (int i = 0; i < 4; ++i){
            float r_ = sigm_(gx[rt][0][i]);
            float z_ = sigm_(gx[rt][1][i]);
            float n_ = tanhfast_(gx[rt][2][i] + r_ * bh2);
            h[rt][i] = (1.f - z_) * n_;
        }

#pragma unroll 1
    for (int step = 1; step < NSTEP; ++step){
        const int p = step & 1;
        /* write h -> Al[p] swizzled; row = rt*16+q*4+i so row&3 == i */
#pragma unroll
        for (int rt = 0; rt < 2; ++rt)
#pragma unroll
            for (int i = 0; i < 4; ++i)
                Al[p][(rt*16 + q*4 + i)*136 + ((c16 ^ (i << 2)) << 3) + cb7]
                    = (ushort_t)bfbits(h[rt][i]);
        __syncthreads();

        f32x4 gh[2][3];
#pragma unroll
        for (int rt = 0; rt < 2; ++rt)
#pragma unroll
            for (int g = 0; g < 3; ++g)
                gh[rt][g] = (f32x4){0.f, 0.f, 0.f, 0.f};
#pragma unroll
        for (int ks = 0; ks < 4; ++ks){
            bf16x8 a[2];
#pragma unroll
            for (int rt = 0; rt < 2; ++rt)
                a[rt] = *reinterpret_cast<const bf16x8*>(
                    &Al[p][(rt*16 + m)*136 + (((ks << 5) ^ xr5) + q8)]);
#pragma unroll
            for (int rt = 0; rt < 2; ++rt)
#pragma unroll
                for (int g = 0; g < 3; ++g)
                    gh[rt][g] = mfma16(a[rt], wf[g][ks], gh[rt][g]);
        }
#pragma unroll
        for (int rt = 0; rt < 2; ++rt)
#pragma unroll
            for (int i = 0; i < 4; ++i){
                float r_ = sigm_(gx[rt][0][i] + gh[rt][0][i]);
                float z_ = sigm_(gx[rt][1][i] + gh[rt][1][i]);
                float n_ = tanhfast_(gx[rt][2][i] + r_ * (gh[rt][2][i] + bh2));
                h[rt][i] = (1.f - z_) * n_ + z_ * h[rt][i];
            }
    }

    /* write h_last to Al[1] for heads (Al[1] last read at step 3, pre-step-4 barrier) */
#pragma unroll
    for (int rt = 0; rt < 2; ++rt)
#pragma unroll
        for (int i = 0; i < 4; ++i)
            Al[1][(rt*16 + q*4 + i)*136 + ((c16 ^ (i << 2)) << 3) + cb7]
                = (ushort_t)bfbits(h[rt][i]);
    __syncthreads();

    /* heads phase 1: 16 threads/row reduce h.W_heads; part==0 stores eta/mu/inv */
    {
        const int r = tid >> 4, part = tid & 15;
        const int rbase = r*136 + ((part ^ ((r & 3) << 2)) << 3);  /* swizzled chunk */
        float a0 = 0.f, a1 = 0.f, a2 = 0.f;
#pragma unroll
        for (int kk = 0; kk < 8; ++kk){
            int k = part*8 + kk;
            float hv = b2f(Al[1][rbase + kk]);
            a0 += hv * Whl[k*3 + 0];
            a1 += hv * Whl[k*3 + 1];
            a2 += hv * Whl[k*3 + 2];
        }
#pragma unroll
        for (int o = 8; o > 0; o >>= 1){
            a0 += __shfl_down(a0, o, 64);
            a1 += __shfl_down(a1, o, 64);
            a2 += __shfl_down(a2, o, 64);
        }
        if (part == 0){
            eLds[r] = softplus_(a0 + bheads[0]);
            mLds[r] = a1 + bheads[1];
            iLds[r] = frcp_(softplus_(a2 + bheads[2]) + 1e-3f);
        }
    }
    __syncthreads();

    /* heads phase 2: 8 lanes/row, one horizon per lane (l2<5 active) */
    float lterm = 0.f;
    {
        const int r2 = tid >> 3, l2 = tid & 7;
        const int gr2 = rowbase + (r2 & (GRU_ROWS-1));
        const bool act = (r2 < GRU_ROWS) && (l2 < 5) && (gr2 < MROWS_GRU);
        float yc = 0.f, eta = 0.f, mu = 0.f, inv = 0.f;
        if (act){
            eta = eLds[r2]; mu = mLds[r2]; inv = iLds[r2];
            float lh = (l2 == 0) ? 0.f :
                       (l2 == 1) ? 0.69314718f :
                       (l2 == 2) ? 1.09861229f :
                       (l2 == 3) ? 1.38629436f : 1.60943791f;
            float zz  = (lh - mu) * inv;
            float cdf = 0.5f * erfcf(-zz * 0.70710678f);
            yc = eta * cdf;
        }
        float prev = __shfl_up(yc, 1, 64);
        if (act){
            if (l2 == 0) prev = 0.f;
            int yy = gr2 / N_;
            int n  = gr2 - yy * N_;
            int yr = years[yy];
            float ytrue = Yv[((size_t)(yr*N_ + n)) * L_ + l2];
            float yh = yc - prev;
            float d  = log1pf(ytrue + 1.0f) - log1pf(yh);
            lterm = d * d;
        }
    }
    lterm = wave_sum(lterm);
    if (lane == 0) red[wv] = lterm;
    __syncthreads();
    if (tid == 0){
        float t = 0.f;
#pragma unroll
        for (int w2 = 0; w2 < 8; ++w2) t += red[w2];
        atomicAdd(&accv[1], t);
    }
}

/* ---- finalize ---- */
__global__ void fin_kernel(const float* __restrict__ accv, float* __restrict__ out)
{
    out[0] = accv[1] * (1.f / (float)(YR_*N_*L_)) +
             1e-3f * accv[0] * (1.f / (float)((T_-1)*N_));
}

extern "C" void kernel_launch(void* const* d_in, const int* in_sizes, int n_in,
                              void* d_out, int out_size, void* d_ws, size_t ws_size,
                              hipStream_t stream)
{
    (void)in_sizes; (void)n_in; (void)out_size; (void)ws_size;
    const float* X       = (const float*)d_in[0];
    const float* W_enc   = (const float*)d_in[1];
    const float* W_ih    = (const float*)d_in[2];
    const float* W_hh    = (const float*)d_in[3];
    const float* b_ih    = (const float*)d_in[4];
    const float* b_hh    = (const float*)d_in[5];
    const float* W_heads = (const float*)d_in[6];
    const float* b_heads = (const float*)d_in[7];
    const float* Yv      = (const float*)d_in[8];
    const int*   years   = (const int*)d_in[9];

    char* ws = (char*)d_ws;
    ushort_t* emb  = (ushort_t*)(ws + OFF_EMB);
    ushort_t* Wet  = (ushort_t*)(ws + OFF_WENC);
    ushort_t* Wiht = (ushort_t*)(ws + OFF_WIH);
    ushort_t* Whht = (ushort_t*)(ws + OFF_WHH);
    float*    accv = (float*)(ws + OFF_ACC);

    prep_kernel<<<192, 256, 0, stream>>>(W_enc, W_ih, W_hh, Wet, Wiht, Whht, accv);
    enc_kernel<<<(MROWS_ENC + 127)/128, 256, 0, stream>>>(X, Wet, emb);
    ltime_kernel<<<(N_*16)/256, 256, 0, stream>>>(emb, accv);
    gru_kernel<<<(MROWS_GRU + GRU_ROWS - 1)/GRU_ROWS, 512, 0, stream>>>(
        emb, Wiht, Whht, b_ih, b_hh, W_heads, b_heads, Yv, years, accv);
    fin_kernel<<<1, 1, 0, stream>>>(accv, (float*)d_out);
}

// Round 4
// 621.128 us; speedup vs baseline: 1.1606x; 1.1606x over previous
//
#include <hip/hip_runtime.h>

typedef unsigned short ushort_t;
typedef __bf16 bf16x8 __attribute__((ext_vector_type(8)));
typedef float f32x4 __attribute__((ext_vector_type(4)));

#define T_ 10
#define N_ 30000
#define F_ 256
#define H_ 128
#define L_ 5
#define YR_ 5
#define NSTEP 5
#define MROWS_ENC (T_*N_)      /* 300000 */
#define MROWS_GRU (YR_*N_)     /* 150000 */
#define GRU_ROWS 32            /* rows per block -> 2 blocks/CU */

/* ---- workspace layout (bytes) ---- */
#define OFF_EMB   ((size_t)0)
#define SZ_EMB    ((size_t)T_*N_*H_*2)          /* 76,800,000 */
#define OFF_WENC  (OFF_EMB + SZ_EMB)
#define SZ_WENC   ((size_t)F_*H_*2)             /* 65,536 */
#define OFF_WIH   (OFF_WENC + SZ_WENC)
#define SZ_W3H    ((size_t)H_*3*H_*2)           /* 98,304 */
#define OFF_WHH   (OFF_WIH + SZ_W3H)
#define OFF_ACC   (OFF_WHH + SZ_W3H)            /* 2 floats: [0]=l_time_sum, [1]=l_pred_sum */

/* ---- helpers ---- */
__device__ __forceinline__ unsigned int bfbits(float x){
    unsigned int u = __float_as_uint(x);
    return (u + 0x7fffu + ((u >> 16) & 1u)) >> 16;   /* RNE f32->bf16 */
}
__device__ __forceinline__ unsigned int pack2(float lo, float hi){
    return bfbits(lo) | (bfbits(hi) << 16);
}
__device__ __forceinline__ float b2f(ushort_t u){
    return __uint_as_float(((unsigned int)u) << 16);
}
__device__ __forceinline__ f32x4 mfma16(bf16x8 a, bf16x8 b, f32x4 c){
    return __builtin_amdgcn_mfma_f32_16x16x32_bf16(a, b, c, 0, 0, 0);
}
__device__ __forceinline__ float fexp2_(float x){ return __builtin_amdgcn_exp2f(x); }
__device__ __forceinline__ float frcp_(float x){ return __builtin_amdgcn_rcpf(x); }
__device__ __forceinline__ float flog2_(float x){ return __builtin_amdgcn_logf(x); }
__device__ __forceinline__ float sigm_(float x){ return frcp_(1.f + fexp2_(-1.44269504f*x)); }
__device__ __forceinline__ float tanhfast_(float x){ return 1.f - 2.f*frcp_(1.f + fexp2_(2.88539008f*x)); }
/* softplus via hw log: arg of log2 is in (1,2], abs err ~1e-7 */
__device__ __forceinline__ float softplus_(float x){
    float ax = fabsf(x);
    return fmaxf(x, 0.f) + 0.69314718f * flog2_(1.f + fexp2_(-1.44269504f*ax));
}
__device__ __forceinline__ float wave_sum(float v){
#pragma unroll
    for (int o = 32; o > 0; o >>= 1) v += __shfl_down(v, o, 64);
    return v;
}
/* LDS-only barrier: waits ds ops but leaves global prefetch loads (vmcnt) in
   flight across the barrier (unlike __syncthreads(), which drains vmcnt(0)). */
__device__ __forceinline__ void bar_lds(){
    asm volatile("s_waitcnt lgkmcnt(0)" ::: "memory");
    __builtin_amdgcn_s_barrier();
    __builtin_amdgcn_sched_barrier(0);
}

/* ---- prep: transpose+convert weights to bf16, zero accumulators ---- */
__global__ void prep_kernel(const float* __restrict__ We, const float* __restrict__ Wih,
                            const float* __restrict__ Whh,
                            ushort_t* __restrict__ Wet, ushort_t* __restrict__ Wiht,
                            ushort_t* __restrict__ Whht, float* __restrict__ accv)
{
    int i = blockIdx.x * 256 + threadIdx.x;
    if (i < 2) accv[i] = 0.f;
    if (i < F_*H_){                       /* Wet[h][f] = We[f][h] */
        int h = i >> 8, f = i & 255;
        Wet[i] = (ushort_t)bfbits(We[f*H_ + h]);
    }
    if (i < 3*H_*H_){                     /* W*t[c][k] = W[k][c] */
        int c = i >> 7, k = i & 127;
        Wiht[i] = (ushort_t)bfbits(Wih[k*(3*H_) + c]);
        Whht[i] = (ushort_t)bfbits(Whh[k*(3*H_) + c]);
    }
}

/* ---- encoder: emb = relu(X @ W_enc), bf16 out [T*N][128] ---- */
__global__ __launch_bounds__(256, 2) void enc_kernel(const float* __restrict__ X,
                                                     const ushort_t* __restrict__ Wet,
                                                     ushort_t* __restrict__ emb)
{
    __shared__ __attribute__((aligned(16))) ushort_t Xl[128*40];  /* [row][k] pitch 40 */
    __shared__ __attribute__((aligned(16))) ushort_t Wl[128*40];  /* [col][k] pitch 40 */
    const int tid = threadIdx.x;
    const int wv = tid >> 6, lane = tid & 63;
    const int m = lane & 15, q = lane >> 4;
    const int rowbase = blockIdx.x * 128;

    f32x4 acc[8][2];
#pragma unroll
    for (int a = 0; a < 8; ++a)
#pragma unroll
        for (int b = 0; b < 2; ++b)
            acc[a][b] = (f32x4){0.f, 0.f, 0.f, 0.f};

    const int srow = tid >> 1, shalf = tid & 1;
    int xrow = rowbase + srow; if (xrow > MROWS_ENC - 1) xrow = MROWS_ENC - 1;
    const float*    xp   = X   + (size_t)xrow * F_ + shalf * 16;
    const ushort_t* wp   = Wet + srow * F_ + shalf * 16;
    ushort_t*       xdst = &Xl[srow * 40 + shalf * 16];
    ushort_t*       wdst = &Wl[srow * 40 + shalf * 16];

    /* prologue: load ks=0 chunk into registers */
    float4 v0 = *(const float4*)(xp);
    float4 v1 = *(const float4*)(xp + 4);
    float4 v2 = *(const float4*)(xp + 8);
    float4 v3 = *(const float4*)(xp + 12);
    uint4  w0 = *(const uint4*)(wp);
    uint4  w1 = *(const uint4*)(wp + 8);

    for (int ks = 0; ks < 8; ++ks){
        /* pack current chunk -> LDS */
        uint4 p0, p1;
        p0.x = pack2(v0.x, v0.y); p0.y = pack2(v0.z, v0.w);
        p0.z = pack2(v1.x, v1.y); p0.w = pack2(v1.z, v1.w);
        p1.x = pack2(v2.x, v2.y); p1.y = pack2(v2.z, v2.w);
        p1.z = pack2(v3.x, v3.y); p1.w = pack2(v3.z, v3.w);
        *(uint4*)xdst       = p0;
        *(uint4*)(xdst + 8) = p1;
        *(uint4*)wdst       = w0;
        *(uint4*)(wdst + 8) = w1;

        /* prefetch next chunk (issued before the MFMA phase; consumed next iter) */
        if (ks < 7){
            const float*    xs   = xp + (ks + 1) * 32;
            const ushort_t* wsrc = wp + (ks + 1) * 32;
            v0 = *(const float4*)(xs);
            v1 = *(const float4*)(xs + 4);
            v2 = *(const float4*)(xs + 8);
            v3 = *(const float4*)(xs + 12);
            w0 = *(const uint4*)(wsrc);
            w1 = *(const uint4*)(wsrc + 8);
        }

        bar_lds();   /* writes visible; prefetch stays in flight */

        bf16x8 af[8];
#pragma unroll
        for (int rt = 0; rt < 8; ++rt)
            af[rt] = *reinterpret_cast<const bf16x8*>(&Xl[(rt*16 + m)*40 + q*8]);
        bf16x8 b0 = *reinterpret_cast<const bf16x8*>(&Wl[(wv*32 +      m)*40 + q*8]);
        bf16x8 b1 = *reinterpret_cast<const bf16x8*>(&Wl[(wv*32 + 16 + m)*40 + q*8]);
#pragma unroll
        for (int rt = 0; rt < 8; ++rt){
            acc[rt][0] = mfma16(af[rt], b0, acc[rt][0]);
            acc[rt][1] = mfma16(af[rt], b1, acc[rt][1]);
        }

        bar_lds();   /* reads done before next iteration's staging writes */
    }

#pragma unroll
    for (int rt = 0; rt < 8; ++rt)
#pragma unroll
        for (int ct = 0; ct < 2; ++ct){
            const int col = wv*32 + ct*16 + m;
#pragma unroll
            for (int i = 0; i < 4; ++i){
                int row = rowbase + rt*16 + q*4 + i;
                if (row < MROWS_ENC){
                    float v = acc[rt][ct][i];
                    v = v > 0.f ? v : 0.f;
                    emb[(size_t)row * H_ + col] = (ushort_t)bfbits(v);
                }
            }
        }
}

/* ---- l_time: mean_n,t sum_h (emb[t]-emb[t+1])^2 ---- */
__global__ __launch_bounds__(256) void ltime_kernel(const ushort_t* __restrict__ emb,
                                                    float* __restrict__ accv)
{
    const int g = blockIdx.x * 256 + threadIdx.x;   /* 480000 = 30000*16 chunks of 8 */
    const int base = g * 8;
    float s = 0.f;
    uint4 pv = *(const uint4*)(emb + base);
#pragma unroll
    for (int t = 1; t < T_; ++t){
        uint4 cv = *(const uint4*)(emb + (size_t)t * N_ * H_ + base);
        const unsigned int pa[4] = {pv.x, pv.y, pv.z, pv.w};
        const unsigned int ca[4] = {cv.x, cv.y, cv.z, cv.w};
#pragma unroll
        for (int j = 0; j < 4; ++j){
            float al = __uint_as_float(pa[j] << 16), ah = __uint_as_float(pa[j] & 0xffff0000u);
            float bl = __uint_as_float(ca[j] << 16), bh = __uint_as_float(ca[j] & 0xffff0000u);
            float d0 = al - bl, d1 = ah - bh;
            s += d0*d0 + d1*d1;
        }
        pv = cv;
    }
    s = wave_sum(s);
    __shared__ float red[4];
    const int lane = threadIdx.x & 63, wv = threadIdx.x >> 6;
    if (lane == 0) red[wv] = s;
    __syncthreads();
    if (threadIdx.x == 0) atomicAdd(&accv[0], red[0] + red[1] + red[2] + red[3]);
}

/* ---- GRU + heads + prediction loss ----
   Round-2 skeleton (linear Al, pitch 136, no swizzle: wave64 b128 has an
   8-clk LDS floor anyway; the r3 swizzle spilled to scratch at the 128-reg
   cap). Recurrent steps FULLY UNROLLED with static A0/A1 parity: no runtime
   buffer index, no loop overhead, one barrier per step. Heads: phase 1
   reduces h.W_heads (all 512 threads, vector b128 LDS reads), phase 2 runs
   on 4 waves only, one horizon per lane, erfc chain issued by half the
   waves; log1p replaced by hw v_log (args >= 1, abs err ~1e-7). */
__global__ __launch_bounds__(512, 4) void gru_kernel(const ushort_t* __restrict__ emb,
                                                     const ushort_t* __restrict__ Wiht,
                                                     const ushort_t* __restrict__ Whht,
                                                     const float* __restrict__ bih,
                                                     const float* __restrict__ bhh,
                                                     const float* __restrict__ Wheads,
                                                     const float* __restrict__ bheads,
                                                     const float* __restrict__ Yv,
                                                     const int* __restrict__ years,
                                                     float* __restrict__ accv)
{
    __shared__ __attribute__((aligned(16))) ushort_t Al[2][GRU_ROWS*136];  /* pitch 136 */
    __shared__ float Whl[3*H_];
    __shared__ float red[8];
    __shared__ float eLds[GRU_ROWS], mLds[GRU_ROWS], iLds[GRU_ROWS];
    const int tid = threadIdx.x;
    const int wv = tid >> 6, lane = tid & 63;
    const int m = lane & 15, q = lane >> 4;
    const int rowbase = blockIdx.x * GRU_ROWS;
    ushort_t* const A0 = Al[0];
    ushort_t* const A1 = Al[1];

    if (tid < 3*H_) Whl[tid] = Wheads[tid];

    /* per-lane gate biases (column = g*128 + wv*16 + m); bh0/bh1 folded into gx */
    const int cb = wv*16 + m;
    const float bi0 = bih[cb] + bhh[cb];
    const float bi1 = bih[128 + cb] + bhh[128 + cb];
    const float bi2 = bih[256 + cb];
    const float bh2 = bhh[256 + cb];

    /* W_ih fragments in registers: wave owns cols [16*wv,16*wv+16) of each gate */
    bf16x8 wf[3][4];
#pragma unroll
    for (int g = 0; g < 3; ++g)
#pragma unroll
        for (int ks = 0; ks < 4; ++ks)
            wf[g][ks] = *reinterpret_cast<const bf16x8*>(
                Wiht + (size_t)(g*128 + cb)*H_ + ks*32 + q*8);

    /* stage v tile (gathered rows of emb) into A0: 32 rows x 16 uint4 = 512 */
    {
        int r = tid >> 4, ch = tid & 15;
        int gr = rowbase + r; if (gr > MROWS_GRU - 1) gr = MROWS_GRU - 1;
        int yy = gr / N_;
        int n  = gr - yy * N_;
        int yr = years[yy];
        uint4 d = *(const uint4*)(emb + ((size_t)(yr*N_ + n))*H_ + ch*8);
        *(uint4*)&A0[r*136 + ch*8] = d;
    }
    __syncthreads();

    /* gx = v @ W_ih + b_ih (+ b_hh for r,z gates) */
    f32x4 gx[2][3];
#pragma unroll
    for (int rt = 0; rt < 2; ++rt)
#pragma unroll
        for (int g = 0; g < 3; ++g)
            gx[rt][g] = (f32x4){0.f, 0.f, 0.f, 0.f};
#pragma unroll
    for (int ks = 0; ks < 4; ++ks){
        bf16x8 a[2];
#pragma unroll
        for (int rt = 0; rt < 2; ++rt)
            a[rt] = *reinterpret_cast<const bf16x8*>(&A0[(rt*16 + m)*136 + ks*32 + q*8]);
#pragma unroll
        for (int rt = 0; rt < 2; ++rt)
#pragma unroll
            for (int g = 0; g < 3; ++g)
                gx[rt][g] = mfma16(a[rt], wf[g][ks], gx[rt][g]);
    }
#pragma unroll
    for (int rt = 0; rt < 2; ++rt)
#pragma unroll
        for (int i = 0; i < 4; ++i){
            gx[rt][0][i] += bi0; gx[rt][1][i] += bi1; gx[rt][2][i] += bi2;
        }

    /* swap register weights to W_hh */
#pragma unroll
    for (int g = 0; g < 3; ++g)
#pragma unroll
        for (int ks = 0; ks < 4; ++ks)
            wf[g][ks] = *reinterpret_cast<const bf16x8*>(
                Whht + (size_t)(g*128 + cb)*H_ + ks*32 + q*8);

    f32x4 h[2];
    /* step 0: h = 0 -> gh = 0 -> h = (1-z)*n */
#pragma unroll
    for (int rt = 0; rt < 2; ++rt)
#pragma unroll
        for (int i = 0; i < 4; ++i){
            float r_ = sigm_(gx[rt][0][i]);
            float z_ = sigm_(gx[rt][1][i]);
            float n_ = tanhfast_(gx[rt][2][i] + r_ * bh2);
            h[rt][i] = (1.f - z_) * n_;
        }

    /* steps 1..4, fully unrolled, static buffer parity B1,B0,B1,B0.
       Safety: one barrier per step; the buffer written at step k was last
       read two phases earlier (>= one barrier in between). */
#define GRU_STEP(BUF)                                                          \
    {                                                                          \
        _Pragma("unroll")                                                      \
        for (int rt = 0; rt < 2; ++rt)                                         \
            _Pragma("unroll")                                                  \
            for (int i = 0; i < 4; ++i)                                        \
                (BUF)[(rt*16 + q*4 + i)*136 + cb] = (ushort_t)bfbits(h[rt][i]);\
        __syncthreads();                                                       \
        f32x4 gh[2][3];                                                        \
        _Pragma("unroll")                                                      \
        for (int rt = 0; rt < 2; ++rt)                                         \
            _Pragma("unroll")                                                  \
            for (int g = 0; g < 3; ++g)                                        \
                gh[rt][g] = (f32x4){0.f, 0.f, 0.f, 0.f};                       \
        _Pragma("unroll")                                                      \
        for (int ks = 0; ks < 4; ++ks){                                        \
            bf16x8 a[2];                                                       \
            _Pragma("unroll")                                                  \
            for (int rt = 0; rt < 2; ++rt)                                     \
                a[rt] = *reinterpret_cast<const bf16x8*>(                      \
                    &(BUF)[(rt*16 + m)*136 + ks*32 + q*8]);                    \
            _Pragma("unroll")                                                  \
            for (int rt = 0; rt < 2; ++rt)                                     \
                _Pragma("unroll")                                              \
                for (int g = 0; g < 3; ++g)                                    \
                    gh[rt][g] = mfma16(a[rt], wf[g][ks], gh[rt][g]);           \
        }                                                                      \
        _Pragma("unroll")                                                      \
        for (int rt = 0; rt < 2; ++rt)                                         \
            _Pragma("unroll")                                                  \
            for (int i = 0; i < 4; ++i){                                       \
                float r_ = sigm_(gx[rt][0][i] + gh[rt][0][i]);                 \
                float z_ = sigm_(gx[rt][1][i] + gh[rt][1][i]);                 \
                float n_ = tanhfast_(gx[rt][2][i] + r_ * (gh[rt][2][i] + bh2));\
                h[rt][i] = (1.f - z_) * n_ + z_ * h[rt][i];                    \
            }                                                                  \
    }

    GRU_STEP(A1)   /* step 1 */
    GRU_STEP(A0)   /* step 2 */
    GRU_STEP(A1)   /* step 3 */
    GRU_STEP(A0)   /* step 4 */
#undef GRU_STEP

    /* write h_last to A1 for heads (A1 last read at step 3; step-4 barrier
       intervened) */
#pragma unroll
    for (int rt = 0; rt < 2; ++rt)
#pragma unroll
        for (int i = 0; i < 4; ++i)
            A1[(rt*16 + q*4 + i)*136 + cb] = (ushort_t)bfbits(h[rt][i]);
    __syncthreads();

    /* heads phase 1: 16 threads/row reduce h.W_heads via one b128 LDS read */
    {
        const int r = tid >> 4, part = tid & 15;
        uint4 hv4 = *(const uint4*)&A1[r*136 + part*8];
        const unsigned int ha[4] = {hv4.x, hv4.y, hv4.z, hv4.w};
        float a0 = 0.f, a1 = 0.f, a2 = 0.f;
#pragma unroll
        for (int j = 0; j < 4; ++j){
            int k = part*8 + j*2;
            float hlo = __uint_as_float(ha[j] << 16);
            float hhi = __uint_as_float(ha[j] & 0xffff0000u);
            a0 += hlo * Whl[k*3 + 0] + hhi * Whl[(k+1)*3 + 0];
            a1 += hlo * Whl[k*3 + 1] + hhi * Whl[(k+1)*3 + 1];
            a2 += hlo * Whl[k*3 + 2] + hhi * Whl[(k+1)*3 + 2];
        }
#pragma unroll
        for (int o = 8; o > 0; o >>= 1){
            a0 += __shfl_down(a0, o, 64);
            a1 += __shfl_down(a1, o, 64);
            a2 += __shfl_down(a2, o, 64);
        }
        if (part == 0){
            eLds[r] = softplus_(a0 + bheads[0]);
            mLds[r] = a1 + bheads[1];
            iLds[r] = frcp_(softplus_(a2 + bheads[2]) + 1e-3f);
        }
    }
    __syncthreads();

    /* heads phase 2: 8 lanes/row on 4 waves (tid<256), one horizon per lane */
    float lterm = 0.f;
    {
        const int r2 = tid >> 3, l2 = tid & 7;
        const int gr2 = rowbase + (r2 & (GRU_ROWS-1));
        const bool act = (r2 < GRU_ROWS) && (l2 < 5) && (gr2 < MROWS_GRU);
        float yc = 0.f;
        if (act){
            float eta = eLds[r2], mu = mLds[r2], inv = iLds[r2];
            float lh = (l2 == 0) ? 0.f :
                       (l2 == 1) ? 0.69314718f :
                       (l2 == 2) ? 1.09861229f :
                       (l2 == 3) ? 1.38629436f : 1.60943791f;
            float zz  = (lh - mu) * inv;
            float cdf = 0.5f * erfcf(-zz * 0.70710678f);
            yc = eta * cdf;
        }
        float prev = __shfl_up(yc, 1, 64);
        if (act){
            if (l2 == 0) prev = 0.f;
            int yy = gr2 / N_;
            int n  = gr2 - yy * N_;
            int yr = years[yy];
            float ytrue = Yv[((size_t)(yr*N_ + n)) * L_ + l2];
            float yh = yc - prev;
            /* log1p(ytrue+1) = ln2*log2(ytrue+2), arg>=2 -> hw log safe;
               log1p(yh) = ln2*log2(1+yh), yh>=0 */
            float d = 0.69314718f * (flog2_(ytrue + 2.0f) - flog2_(1.0f + yh));
            lterm = d * d;
        }
    }
    lterm = wave_sum(lterm);
    if (lane == 0) red[wv] = lterm;
    __syncthreads();
    if (tid == 0){
        float t = 0.f;
#pragma unroll
        for (int w2 = 0; w2 < 8; ++w2) t += red[w2];
        atomicAdd(&accv[1], t);
    }
}

/* ---- finalize ---- */
__global__ void fin_kernel(const float* __restrict__ accv, float* __restrict__ out)
{
    out[0] = accv[1] * (1.f / (float)(YR_*N_*L_)) +
             1e-3f * accv[0] * (1.f / (float)((T_-1)*N_));
}

extern "C" void kernel_launch(void* const* d_in, const int* in_sizes, int n_in,
                              void* d_out, int out_size, void* d_ws, size_t ws_size,
                              hipStream_t stream)
{
    (void)in_sizes; (void)n_in; (void)out_size; (void)ws_size;
    const float* X       = (const float*)d_in[0];
    const float* W_enc   = (const float*)d_in[1];
    const float* W_ih    = (const float*)d_in[2];
    const float* W_hh    = (const float*)d_in[3];
    const float* b_ih    = (const float*)d_in[4];
    const float* b_hh    = (const float*)d_in[5];
    const float* W_heads = (const float*)d_in[6];
    const float* b_heads = (const float*)d_in[7];
    const float* Yv      = (const float*)d_in[8];
    const int*   years   = (const int*)d_in[9];

    char* ws = (char*)d_ws;
    ushort_t* emb  = (ushort_t*)(ws + OFF_EMB);
    ushort_t* Wet  = (ushort_t*)(ws + OFF_WENC);
    ushort_t* Wiht = (ushort_t*)(ws + OFF_WIH);
    ushort_t* Whht = (ushort_t*)(ws + OFF_WHH);
    float*    accv = (float*)(ws + OFF_ACC);

    prep_kernel<<<192, 256, 0, stream>>>(W_enc, W_ih, W_hh, Wet, Wiht, Whht, accv);
    enc_kernel<<<(MROWS_ENC + 127)/128, 256, 0, stream>>>(X, Wet, emb);
    ltime_kernel<<<(N_*16)/256, 256, 0, stream>>>(emb, accv);
    gru_kernel<<<(MROWS_GRU + GRU_ROWS - 1)/GRU_ROWS, 512, 0, stream>>>(
        emb, Wiht, Whht, b_ih, b_hh, W_heads, b_heads, Yv, years, accv);
    fin_kernel<<<1, 1, 0, stream>>>(accv, (float*)d_out);
}

// Round 5
// 578.393 us; speedup vs baseline: 1.2463x; 1.0739x over previous
//
#include <hip/hip_runtime.h>

typedef unsigned short ushort_t;
typedef __bf16 bf16x8 __attribute__((ext_vector_type(8)));
typedef float f32x4 __attribute__((ext_vector_type(4)));

#define T_ 10
#define N_ 30000
#define F_ 256
#define H_ 128
#define L_ 5
#define YR_ 5
#define NSTEP 5
#define MROWS_GRU (YR_*N_)     /* 150000 */
#define GRU_ROWS 32            /* rows per block -> 2 blocks/CU */
#define EROWS 64               /* encoder n-rows per block */

/* ---- workspace layout (bytes) ---- */
#define OFF_EMB   ((size_t)0)
#define SZ_EMB    ((size_t)T_*N_*H_*2)          /* 76,800,000 (only t<5 written) */
#define OFF_WENC  (OFF_EMB + SZ_EMB)
#define SZ_WENC   ((size_t)F_*H_*2)             /* 65,536 */
#define OFF_WIH   (OFF_WENC + SZ_WENC)
#define SZ_W3H    ((size_t)H_*3*H_*2)           /* 98,304 */
#define OFF_WHH   (OFF_WIH + SZ_W3H)
#define OFF_ACC   (OFF_WHH + SZ_W3H)            /* 2 floats: [0]=l_time_sum, [1]=l_pred_sum */

/* ---- helpers ---- */
__device__ __forceinline__ unsigned int bfbits(float x){
    unsigned int u = __float_as_uint(x);
    return (u + 0x7fffu + ((u >> 16) & 1u)) >> 16;   /* RNE f32->bf16 */
}
__device__ __forceinline__ unsigned int pack2(float lo, float hi){
    return bfbits(lo) | (bfbits(hi) << 16);
}
__device__ __forceinline__ float b2f(ushort_t u){
    return __uint_as_float(((unsigned int)u) << 16);
}
__device__ __forceinline__ f32x4 mfma16(bf16x8 a, bf16x8 b, f32x4 c){
    return __builtin_amdgcn_mfma_f32_16x16x32_bf16(a, b, c, 0, 0, 0);
}
__device__ __forceinline__ float fexp2_(float x){ return __builtin_amdgcn_exp2f(x); }
__device__ __forceinline__ float frcp_(float x){ return __builtin_amdgcn_rcpf(x); }
__device__ __forceinline__ float flog2_(float x){ return __builtin_amdgcn_logf(x); }
__device__ __forceinline__ float sigm_(float x){ return frcp_(1.f + fexp2_(-1.44269504f*x)); }
__device__ __forceinline__ float tanhfast_(float x){ return 1.f - 2.f*frcp_(1.f + fexp2_(2.88539008f*x)); }
/* softplus via hw log: arg of log2 is in (1,2], abs err ~1e-7 */
__device__ __forceinline__ float softplus_(float x){
    float ax = fabsf(x);
    return fmaxf(x, 0.f) + 0.69314718f * flog2_(1.f + fexp2_(-1.44269504f*ax));
}
__device__ __forceinline__ float wave_sum(float v){
#pragma unroll
    for (int o = 32; o > 0; o >>= 1) v += __shfl_down(v, o, 64);
    return v;
}
/* LDS-only barrier: waits ds ops but leaves global prefetch loads (vmcnt) in
   flight across the barrier (unlike __syncthreads(), which drains vmcnt(0)). */
__device__ __forceinline__ void bar_lds(){
    asm volatile("s_waitcnt lgkmcnt(0)" ::: "memory");
    __builtin_amdgcn_s_barrier();
    __builtin_amdgcn_sched_barrier(0);
}

/* ---- prep: transpose+convert weights to bf16, zero accumulators ---- */
__global__ void prep_kernel(const float* __restrict__ We, const float* __restrict__ Wih,
                            const float* __restrict__ Whh,
                            ushort_t* __restrict__ Wet, ushort_t* __restrict__ Wiht,
                            ushort_t* __restrict__ Whht, float* __restrict__ accv)
{
    int i = blockIdx.x * 256 + threadIdx.x;
    if (i < 2) accv[i] = 0.f;
    if (i < F_*H_){                       /* Wet[h][f] = We[f][h] */
        int h = i >> 8, f = i & 255;
        Wet[i] = (ushort_t)bfbits(We[f*H_ + h]);
    }
    if (i < 3*H_*H_){                     /* W*t[c][k] = W[k][c] */
        int c = i >> 7, k = i & 127;
        Wiht[i] = (ushort_t)bfbits(Wih[k*(3*H_) + c]);
        Whht[i] = (ushort_t)bfbits(Whh[k*(3*H_) + c]);
    }
}

/* ---- fused encoder + l_time: per n-tile, loop t=0..9 ----
   W_enc register-resident per wave (64 VGPRs, loaded once — no W staging).
   X reg-prefetched 1-deep, double-buffered LDS, ONE barrier per ks slice
   (vmcnt stays in flight across it). Previous-t relu output held as packed
   bf16 in 16 registers -> l_time diff computed in-register (bf16-rounded,
   identical numerics to the old separate ltime kernel). emb written only
   for t<5 (t>=5 only feeds l_time). */
__global__ __launch_bounds__(256, 2) void encf_kernel(const float* __restrict__ X,
                                                      const ushort_t* __restrict__ Wet,
                                                      ushort_t* __restrict__ emb,
                                                      float* __restrict__ accv)
{
    __shared__ __attribute__((aligned(16))) ushort_t Xl[2][EROWS*40]; /* pitch 40 */
    __shared__ float red[4];
    const int tid = threadIdx.x;
    const int wv = tid >> 6, lane = tid & 63;
    const int m = lane & 15, q = lane >> 4;
    const int rowbase = blockIdx.x * EROWS;

    /* W_enc fragments: wave wv owns cols [wv*32, wv*32+32) for all K=256 */
    bf16x8 wf[2][8];
#pragma unroll
    for (int ct = 0; ct < 2; ++ct)
#pragma unroll
        for (int ks = 0; ks < 8; ++ks)
            wf[ct][ks] = *reinterpret_cast<const bf16x8*>(
                Wet + (wv*32 + ct*16 + m)*F_ + ks*32 + q*8);

    /* staging geometry: 64 rows x 4 chunks of 8 floats */
    const int sr = tid >> 2, sc = tid & 3;
    int xr = rowbase + sr; if (xr > N_ - 1) xr = N_ - 1;
    const float* xb = X + (size_t)xr * F_ + sc * 8;
    ushort_t* const xd0 = &Xl[0][sr*40 + sc*8];
    ushort_t* const xd1 = &Xl[1][sr*40 + sc*8];

    /* prologue: (t=0, ks=0) chunk in regs */
    float4 a0 = *(const float4*)(xb);
    float4 a1 = *(const float4*)(xb + 4);

    unsigned int pb[4][2][2];   /* prev-t bf16 pairs, 16 regs */
    float s = 0.f;              /* l_time partial */

#pragma unroll 1
    for (int t = 0; t < T_; ++t){
        f32x4 acc[4][2];
#pragma unroll
        for (int rt = 0; rt < 4; ++rt)
#pragma unroll
            for (int ct = 0; ct < 2; ++ct)
                acc[rt][ct] = (f32x4){0.f, 0.f, 0.f, 0.f};

#pragma unroll
        for (int ks = 0; ks < 8; ++ks){
            /* pack current chunk -> LDS buf (ks&1) */
            uint4 p;
            p.x = pack2(a0.x, a0.y); p.y = pack2(a0.z, a0.w);
            p.z = pack2(a1.x, a1.y); p.w = pack2(a1.z, a1.w);
            *(uint4*)((ks & 1) ? xd1 : xd0) = p;

            /* prefetch next chunk (consumed next iteration) */
            {
                int kk = ks + 1, tt = t;
                if (kk == 8){ kk = 0; ++tt; }
                if (tt < T_){
                    const float* xs = xb + (size_t)tt * (N_*F_) + kk*32;
                    a0 = *(const float4*)(xs);
                    a1 = *(const float4*)(xs + 4);
                }
            }

            bar_lds();   /* writes visible; prefetch stays in flight */

            const ushort_t* Xc = Xl[ks & 1];
            bf16x8 af[4];
#pragma unroll
            for (int rt = 0; rt < 4; ++rt)
                af[rt] = *reinterpret_cast<const bf16x8*>(&Xc[(rt*16 + m)*40 + q*8]);
#pragma unroll
            for (int rt = 0; rt < 4; ++rt){
                acc[rt][0] = mfma16(af[rt], wf[0][ks], acc[rt][0]);
                acc[rt][1] = mfma16(af[rt], wf[1][ks], acc[rt][1]);
            }
            /* no trailing barrier: reads of this buf are drained by the
               lgkmcnt(0) in the NEXT bar_lds before the buf is rewritten
               (2 iterations later) */
        }

        /* epilogue for t: relu -> bf16; l_time diff vs prev-t regs; emb t<5 */
#pragma unroll
        for (int rt = 0; rt < 4; ++rt)
#pragma unroll
            for (int ct = 0; ct < 2; ++ct){
                unsigned int cc[4];
#pragma unroll
                for (int i = 0; i < 4; ++i){
                    float v = acc[rt][ct][i];
                    v = v > 0.f ? v : 0.f;
                    cc[i] = bfbits(v);
                }
                const int col = wv*32 + ct*16 + m;
#pragma unroll
                for (int i = 0; i < 4; ++i){
                    const int nrow = rowbase + rt*16 + q*4 + i;
                    const bool valid = nrow < N_;
                    if (t > 0){
                        unsigned int pw = pb[rt][ct][i >> 1];
                        float pf = __uint_as_float((i & 1) ? (pw & 0xffff0000u)
                                                           : (pw << 16));
                        float d = __uint_as_float(cc[i] << 16) - pf;
                        if (valid) s += d * d;
                    }
                    if (t < YR_ && valid)
                        emb[((size_t)(t*N_) + nrow)*H_ + col] = (ushort_t)cc[i];
                }
                pb[rt][ct][0] = cc[0] | (cc[1] << 16);
                pb[rt][ct][1] = cc[2] | (cc[3] << 16);
            }
    }

    s = wave_sum(s);
    if (lane == 0) red[wv] = s;
    __syncthreads();
    if (tid == 0) atomicAdd(&accv[0], red[0] + red[1] + red[2] + red[3]);
}

/* ---- GRU + heads + prediction loss (unchanged from round 4) ---- */
__global__ __launch_bounds__(512, 4) void gru_kernel(const ushort_t* __restrict__ emb,
                                                     const ushort_t* __restrict__ Wiht,
                                                     const ushort_t* __restrict__ Whht,
                                                     const float* __restrict__ bih,
                                                     const float* __restrict__ bhh,
                                                     const float* __restrict__ Wheads,
                                                     const float* __restrict__ bheads,
                                                     const float* __restrict__ Yv,
                                                     const int* __restrict__ years,
                                                     float* __restrict__ accv)
{
    __shared__ __attribute__((aligned(16))) ushort_t Al[2][GRU_ROWS*136];  /* pitch 136 */
    __shared__ float Whl[3*H_];
    __shared__ float red[8];
    __shared__ float eLds[GRU_ROWS], mLds[GRU_ROWS], iLds[GRU_ROWS];
    const int tid = threadIdx.x;
    const int wv = tid >> 6, lane = tid & 63;
    const int m = lane & 15, q = lane >> 4;
    const int rowbase = blockIdx.x * GRU_ROWS;
    ushort_t* const A0 = Al[0];
    ushort_t* const A1 = Al[1];

    if (tid < 3*H_) Whl[tid] = Wheads[tid];

    /* per-lane gate biases (column = g*128 + wv*16 + m); bh0/bh1 folded into gx */
    const int cb = wv*16 + m;
    const float bi0 = bih[cb] + bhh[cb];
    const float bi1 = bih[128 + cb] + bhh[128 + cb];
    const float bi2 = bih[256 + cb];
    const float bh2 = bhh[256 + cb];

    /* W_ih fragments in registers: wave owns cols [16*wv,16*wv+16) of each gate */
    bf16x8 wf[3][4];
#pragma unroll
    for (int g = 0; g < 3; ++g)
#pragma unroll
        for (int ks = 0; ks < 4; ++ks)
            wf[g][ks] = *reinterpret_cast<const bf16x8*>(
                Wiht + (size_t)(g*128 + cb)*H_ + ks*32 + q*8);

    /* stage v tile (gathered rows of emb) into A0: 32 rows x 16 uint4 = 512 */
    {
        int r = tid >> 4, ch = tid & 15;
        int gr = rowbase + r; if (gr > MROWS_GRU - 1) gr = MROWS_GRU - 1;
        int yy = gr / N_;
        int n  = gr - yy * N_;
        int yr = years[yy];
        uint4 d = *(const uint4*)(emb + ((size_t)(yr*N_ + n))*H_ + ch*8);
        *(uint4*)&A0[r*136 + ch*8] = d;
    }
    __syncthreads();

    /* gx = v @ W_ih + b_ih (+ b_hh for r,z gates) */
    f32x4 gx[2][3];
#pragma unroll
    for (int rt = 0; rt < 2; ++rt)
#pragma unroll
        for (int g = 0; g < 3; ++g)
            gx[rt][g] = (f32x4){0.f, 0.f, 0.f, 0.f};
#pragma unroll
    for (int ks = 0; ks < 4; ++ks){
        bf16x8 a[2];
#pragma unroll
        for (int rt = 0; rt < 2; ++rt)
            a[rt] = *reinterpret_cast<const bf16x8*>(&A0[(rt*16 + m)*136 + ks*32 + q*8]);
#pragma unroll
        for (int rt = 0; rt < 2; ++rt)
#pragma unroll
            for (int g = 0; g < 3; ++g)
                gx[rt][g] = mfma16(a[rt], wf[g][ks], gx[rt][g]);
    }
#pragma unroll
    for (int rt = 0; rt < 2; ++rt)
#pragma unroll
        for (int i = 0; i < 4; ++i){
            gx[rt][0][i] += bi0; gx[rt][1][i] += bi1; gx[rt][2][i] += bi2;
        }

    /* swap register weights to W_hh */
#pragma unroll
    for (int g = 0; g < 3; ++g)
#pragma unroll
        for (int ks = 0; ks < 4; ++ks)
            wf[g][ks] = *reinterpret_cast<const bf16x8*>(
                Whht + (size_t)(g*128 + cb)*H_ + ks*32 + q*8);

    f32x4 h[2];
    /* step 0: h = 0 -> gh = 0 -> h = (1-z)*n */
#pragma unroll
    for (int rt = 0; rt < 2; ++rt)
#pragma unroll
        for (int i = 0; i < 4; ++i){
            float r_ = sigm_(gx[rt][0][i]);
            float z_ = sigm_(gx[rt][1][i]);
            float n_ = tanhfast_(gx[rt][2][i] + r_ * bh2);
            h[rt][i] = (1.f - z_) * n_;
        }

    /* steps 1..4, fully unrolled, static buffer parity B1,B0,B1,B0. */
#define GRU_STEP(BUF)                                                          \
    {                                                                          \
        _Pragma("unroll")                                                      \
        for (int rt = 0; rt < 2; ++rt)                                         \
            _Pragma("unroll")                                                  \
            for (int i = 0; i < 4; ++i)                                        \
                (BUF)[(rt*16 + q*4 + i)*136 + cb] = (ushort_t)bfbits(h[rt][i]);\
        __syncthreads();                                                       \
        f32x4 gh[2][3];                                                        \
        _Pragma("unroll")                                                      \
        for (int rt = 0; rt < 2; ++rt)                                         \
            _Pragma("unroll")                                                  \
            for (int g = 0; g < 3; ++g)                                        \
                gh[rt][g] = (f32x4){0.f, 0.f, 0.f, 0.f};                       \
        _Pragma("unroll")                                                      \
        for (int ks = 0; ks < 4; ++ks){                                        \
            bf16x8 a[2];                                                       \
            _Pragma("unroll")                                                  \
            for (int rt = 0; rt < 2; ++rt)                                     \
                a[rt] = *reinterpret_cast<const bf16x8*>(                      \
                    &(BUF)[(rt*16 + m)*136 + ks*32 + q*8]);                    \
            _Pragma("unroll")                                                  \
            for (int rt = 0; rt < 2; ++rt)                                     \
                _Pragma("unroll")                                              \
                for (int g = 0; g < 3; ++g)                                    \
                    gh[rt][g] = mfma16(a[rt], wf[g][ks], gh[rt][g]);           \
        }                                                                      \
        _Pragma("unroll")                                                      \
        for (int rt = 0; rt < 2; ++rt)                                         \
            _Pragma("unroll")                                                  \
            for (int i = 0; i < 4; ++i){                                       \
                float r_ = sigm_(gx[rt][0][i] + gh[rt][0][i]);                 \
                float z_ = sigm_(gx[rt][1][i] + gh[rt][1][i]);                 \
                float n_ = tanhfast_(gx[rt][2][i] + r_ * (gh[rt][2][i] + bh2));\
                h[rt][i] = (1.f - z_) * n_ + z_ * h[rt][i];                    \
            }                                                                  \
    }

    GRU_STEP(A1)   /* step 1 */
    GRU_STEP(A0)   /* step 2 */
    GRU_STEP(A1)   /* step 3 */
    GRU_STEP(A0)   /* step 4 */
#undef GRU_STEP

    /* write h_last to A1 for heads */
#pragma unroll
    for (int rt = 0; rt < 2; ++rt)
#pragma unroll
        for (int i = 0; i < 4; ++i)
            A1[(rt*16 + q*4 + i)*136 + cb] = (ushort_t)bfbits(h[rt][i]);
    __syncthreads();

    /* heads phase 1: 16 threads/row reduce h.W_heads via one b128 LDS read */
    {
        const int r = tid >> 4, part = tid & 15;
        uint4 hv4 = *(const uint4*)&A1[r*136 + part*8];
        const unsigned int ha[4] = {hv4.x, hv4.y, hv4.z, hv4.w};
        float a0 = 0.f, a1 = 0.f, a2 = 0.f;
#pragma unroll
        for (int j = 0; j < 4; ++j){
            int k = part*8 + j*2;
            float hlo = __uint_as_float(ha[j] << 16);
            float hhi = __uint_as_float(ha[j] & 0xffff0000u);
            a0 += hlo * Whl[k*3 + 0] + hhi * Whl[(k+1)*3 + 0];
            a1 += hlo * Whl[k*3 + 1] + hhi * Whl[(k+1)*3 + 1];
            a2 += hlo * Whl[k*3 + 2] + hhi * Whl[(k+1)*3 + 2];
        }
#pragma unroll
        for (int o = 8; o > 0; o >>= 1){
            a0 += __shfl_down(a0, o, 64);
            a1 += __shfl_down(a1, o, 64);
            a2 += __shfl_down(a2, o, 64);
        }
        if (part == 0){
            eLds[r] = softplus_(a0 + bheads[0]);
            mLds[r] = a1 + bheads[1];
            iLds[r] = frcp_(softplus_(a2 + bheads[2]) + 1e-3f);
        }
    }
    __syncthreads();

    /* heads phase 2: 8 lanes/row on 4 waves (tid<256), one horizon per lane */
    float lterm = 0.f;
    {
        const int r2 = tid >> 3, l2 = tid & 7;
        const int gr2 = rowbase + (r2 & (GRU_ROWS-1));
        const bool act = (r2 < GRU_ROWS) && (l2 < 5) && (gr2 < MROWS_GRU);
        float yc = 0.f;
        if (act){
            float eta = eLds[r2], mu = mLds[r2], inv = iLds[r2];
            float lh = (l2 == 0) ? 0.f :
                       (l2 == 1) ? 0.69314718f :
                       (l2 == 2) ? 1.09861229f :
                       (l2 == 3) ? 1.38629436f : 1.60943791f;
            float zz  = (lh - mu) * inv;
            float cdf = 0.5f * erfcf(-zz * 0.70710678f);
            yc = eta * cdf;
        }
        float prev = __shfl_up(yc, 1, 64);
        if (act){
            if (l2 == 0) prev = 0.f;
            int yy = gr2 / N_;
            int n  = gr2 - yy * N_;
            int yr = years[yy];
            float ytrue = Yv[((size_t)(yr*N_ + n)) * L_ + l2];
            float yh = yc - prev;
            float d = 0.69314718f * (flog2_(ytrue + 2.0f) - flog2_(1.0f + yh));
            lterm = d * d;
        }
    }
    lterm = wave_sum(lterm);
    if (lane == 0) red[wv] = lterm;
    __syncthreads();
    if (tid == 0){
        float t = 0.f;
#pragma unroll
        for (int w2 = 0; w2 < 8; ++w2) t += red[w2];
        atomicAdd(&accv[1], t);
    }
}

/* ---- finalize ---- */
__global__ void fin_kernel(const float* __restrict__ accv, float* __restrict__ out)
{
    out[0] = accv[1] * (1.f / (float)(YR_*N_*L_)) +
             1e-3f * accv[0] * (1.f / (float)((T_-1)*N_));
}

extern "C" void kernel_launch(void* const* d_in, const int* in_sizes, int n_in,
                              void* d_out, int out_size, void* d_ws, size_t ws_size,
                              hipStream_t stream)
{
    (void)in_sizes; (void)n_in; (void)out_size; (void)ws_size;
    const float* X       = (const float*)d_in[0];
    const float* W_enc   = (const float*)d_in[1];
    const float* W_ih    = (const float*)d_in[2];
    const float* W_hh    = (const float*)d_in[3];
    const float* b_ih    = (const float*)d_in[4];
    const float* b_hh    = (const float*)d_in[5];
    const float* W_heads = (const float*)d_in[6];
    const float* b_heads = (const float*)d_in[7];
    const float* Yv      = (const float*)d_in[8];
    const int*   years   = (const int*)d_in[9];

    char* ws = (char*)d_ws;
    ushort_t* emb  = (ushort_t*)(ws + OFF_EMB);
    ushort_t* Wet  = (ushort_t*)(ws + OFF_WENC);
    ushort_t* Wiht = (ushort_t*)(ws + OFF_WIH);
    ushort_t* Whht = (ushort_t*)(ws + OFF_WHH);
    float*    accv = (float*)(ws + OFF_ACC);

    prep_kernel<<<192, 256, 0, stream>>>(W_enc, W_ih, W_hh, Wet, Wiht, Whht, accv);
    encf_kernel<<<(N_ + EROWS - 1)/EROWS, 256, 0, stream>>>(X, Wet, emb, accv);
    gru_kernel<<<(MROWS_GRU + GRU_ROWS - 1)/GRU_ROWS, 512, 0, stream>>>(
        emb, Wiht, Whht, b_ih, b_hh, W_heads, b_heads, Yv, years, accv);
    fin_kernel<<<1, 1, 0, stream>>>(accv, (float*)d_out);
}